// Round 2
// baseline (16044.763 us; speedup 1.0000x reference)
//
#include <hip/hip_runtime.h>
#include <cstdint>
#include <math.h>

// ---------------------------------------------------------------------------
// Threefry-2x32-20, exactly as JAX lowers it.
// ---------------------------------------------------------------------------
__device__ __forceinline__ uint32_t rotl32(uint32_t x, uint32_t n) {
    return (x << n) | (x >> (32u - n));
}

__device__ __forceinline__ void tf2x32(uint32_t k0, uint32_t k1,
                                       uint32_t x0, uint32_t x1,
                                       uint32_t& o0, uint32_t& o1) {
    uint32_t k2 = k0 ^ k1 ^ 0x1BD11BDAu;
    x0 += k0; x1 += k1;
    x0 += x1; x1 = rotl32(x1, 13); x1 ^= x0;
    x0 += x1; x1 = rotl32(x1, 15); x1 ^= x0;
    x0 += x1; x1 = rotl32(x1, 26); x1 ^= x0;
    x0 += x1; x1 = rotl32(x1, 6);  x1 ^= x0;
    x0 += k1; x1 += k2 + 1u;
    x0 += x1; x1 = rotl32(x1, 17); x1 ^= x0;
    x0 += x1; x1 = rotl32(x1, 29); x1 ^= x0;
    x0 += x1; x1 = rotl32(x1, 16); x1 ^= x0;
    x0 += x1; x1 = rotl32(x1, 24); x1 ^= x0;
    x0 += k2; x1 += k0 + 2u;
    x0 += x1; x1 = rotl32(x1, 13); x1 ^= x0;
    x0 += x1; x1 = rotl32(x1, 15); x1 ^= x0;
    x0 += x1; x1 = rotl32(x1, 26); x1 ^= x0;
    x0 += x1; x1 = rotl32(x1, 6);  x1 ^= x0;
    x0 += k0; x1 += k1 + 3u;
    x0 += x1; x1 = rotl32(x1, 17); x1 ^= x0;
    x0 += x1; x1 = rotl32(x1, 29); x1 ^= x0;
    x0 += x1; x1 = rotl32(x1, 16); x1 ^= x0;
    x0 += x1; x1 = rotl32(x1, 24); x1 ^= x0;
    x0 += k1; x1 += k2 + 4u;
    x0 += x1; x1 = rotl32(x1, 13); x1 ^= x0;
    x0 += x1; x1 = rotl32(x1, 15); x1 ^= x0;
    x0 += x1; x1 = rotl32(x1, 26); x1 ^= x0;
    x0 += x1; x1 = rotl32(x1, 6);  x1 ^= x0;
    x0 += k2; x1 += k0 + 5u;
    o0 = x0; o1 = x1;
}

// gumbel noise element n for shape (N,), key = split(key(42))[which]
__device__ float gumbel_at(int n, int which, int N) {
    // split(key(42)): counts [0,1,2,3]; pairs (0,2) and (1,3).
    uint32_t a0, a1, b0, b1;
    tf2x32(0u, 42u, 0u, 2u, a0, a1);
    tf2x32(0u, 42u, 1u, 3u, b0, b1);
    uint32_t gk0 = which ? a1 : a0;
    uint32_t gk1 = which ? b1 : b0;
    int half = N >> 1;  // N even (50000)
    uint32_t o0, o1, bits;
    if (n < half) { tf2x32(gk0, gk1, (uint32_t)n, (uint32_t)(n + half), o0, o1); bits = o0; }
    else          { tf2x32(gk0, gk1, (uint32_t)(n - half), (uint32_t)n, o0, o1); bits = o1; }
    float f = __uint_as_float((bits >> 9) | 0x3F800000u) - 1.0f;
    float u = fmaxf(1.17549435e-38f, f);
    return -logf(-logf(u));
}

// monotone float<->uint mapping (zero-init == -NaN, smaller than everything)
__device__ __forceinline__ uint32_t fmono(float f) {
    uint32_t b = __float_as_uint(f);
    return (b & 0x80000000u) ? ~b : (b | 0x80000000u);
}
__device__ __forceinline__ float funmono(uint32_t u) {
    uint32_t b = (u & 0x80000000u) ? (u & 0x7FFFFFFFu) : ~u;
    return __uint_as_float(b);
}

#define NEGF (-1e9f)

// ---------------------------------------------------------------------------
// K1: q/k/v projections. One block per node, 128 threads (one per out col).
// ---------------------------------------------------------------------------
__global__ void k_qkv(const float* __restrict__ xin, const float* __restrict__ nt,
                      const float* __restrict__ rq, int din, int N,
                      const float* __restrict__ Wq, const float* __restrict__ bq,
                      const float* __restrict__ Wk, const float* __restrict__ bk,
                      const float* __restrict__ Wv, const float* __restrict__ bv,
                      float* __restrict__ Q, float* __restrict__ K, float* __restrict__ V) {
    int n = blockIdx.x;
    int j = threadIdx.x;
    __shared__ float xs[32];
    if (j < din) xs[j] = (din == 2) ? (j == 0 ? nt[n] : rq[n]) : xin[(size_t)n * din + j];
    __syncthreads();
    float q = bq[j], k = bk[j], v = bv[j];
    for (int d = 0; d < din; d++) {
        float x = xs[d];
        q = fmaf(x, Wq[d * 128 + j], q);
        k = fmaf(x, Wk[d * 128 + j], k);
        v = fmaf(x, Wv[d * 128 + j], v);
    }
    size_t o = (size_t)n * 128 + j;
    Q[o] = q; K[o] = k; V[o] = v;
}

// ---------------------------------------------------------------------------
// K2: per-(edge,head) attention score + segment max via monotone atomicMax.
// ---------------------------------------------------------------------------
__global__ void k_alpha(const int* __restrict__ src, const int* __restrict__ dst,
                        const float* __restrict__ lat,
                        const float* __restrict__ Q, const float* __restrict__ Kb,
                        const float* __restrict__ We,
                        float* __restrict__ ALPHA, unsigned int* __restrict__ AMAXU, int E) {
    int t = blockIdx.x * blockDim.x + threadIdx.x;
    if (t >= E * 4) return;
    int e = t >> 2, h = t & 3;
    int s = src[e], d = dst[e];
    float l = lat[e];
    const float4* qp = (const float4*)(Q + (size_t)d * 128 + h * 32);
    const float4* kp = (const float4*)(Kb + (size_t)s * 128 + h * 32);
    const float4* wp = (const float4*)(We + h * 32);
    float acc = 0.f;
#pragma unroll
    for (int i = 0; i < 8; i++) {
        float4 q4 = qp[i], k4 = kp[i], w4 = wp[i];
        acc += q4.x * fmaf(l, w4.x, k4.x);
        acc += q4.y * fmaf(l, w4.y, k4.y);
        acc += q4.z * fmaf(l, w4.z, k4.z);
        acc += q4.w * fmaf(l, w4.w, k4.w);
    }
    acc *= 0.17677669529663687f;  // 1/sqrt(32)
    ALPHA[t] = acc;
    atomicMax(&AMAXU[(size_t)d * 4 + h], fmono(acc));
}

// ---------------------------------------------------------------------------
// K3: per-(edge,head) exp weight, scatter-add numerator (32 ch) + denominator.
// ---------------------------------------------------------------------------
__global__ void k_accum(const int* __restrict__ src, const int* __restrict__ dst,
                        const float* __restrict__ lat,
                        const float* __restrict__ Vb, const float* __restrict__ We,
                        const float* __restrict__ ALPHA, const unsigned int* __restrict__ AMAXU,
                        float* __restrict__ NUM, float* __restrict__ DEN, int E) {
    int t = blockIdx.x * blockDim.x + threadIdx.x;
    if (t >= E * 4) return;
    int e = t >> 2, h = t & 3;
    int s = src[e], d = dst[e];
    float amax = funmono(AMAXU[(size_t)d * 4 + h]);
    float w = expf(ALPHA[t] - amax);
    atomicAdd(&DEN[(size_t)d * 4 + h], w);
    float l = lat[e];
    const float4* vp = (const float4*)(Vb + (size_t)s * 128 + h * 32);
    const float4* wp = (const float4*)(We + h * 32);
    float* np_ = NUM + (size_t)d * 128 + h * 32;
#pragma unroll
    for (int i = 0; i < 8; i++) {
        float4 v4 = vp[i], w4 = wp[i];
        atomicAdd(np_ + i * 4 + 0, fmaf(l, w4.x, v4.x) * w);
        atomicAdd(np_ + i * 4 + 1, fmaf(l, w4.y, v4.y) * w);
        atomicAdd(np_ + i * 4 + 2, fmaf(l, w4.z, v4.z) * w);
        atomicAdd(np_ + i * 4 + 3, fmaf(l, w4.w, v4.w) * w);
    }
}

// ---------------------------------------------------------------------------
// K4: normalize, compute xr = x@Ws+bs, beta gate, write layer output.
// One block per node, 128 threads.
// ---------------------------------------------------------------------------
__global__ void k_combine(const float* __restrict__ xin, const float* __restrict__ nt,
                          const float* __restrict__ rq, int din, int N,
                          const float* __restrict__ Ws, const float* __restrict__ bs,
                          const float* __restrict__ Wb,
                          const float* __restrict__ NUM, const float* __restrict__ DEN,
                          float* __restrict__ A) {
    int n = blockIdx.x;
    int j = threadIdx.x;
    __shared__ float xs[32];
    __shared__ float red[128];
    if (j < din) xs[j] = (din == 2) ? (j == 0 ? nt[n] : rq[n]) : xin[(size_t)n * din + j];
    __syncthreads();
    float r = bs[j];
    for (int d = 0; d < din; d++) r = fmaf(xs[d], Ws[d * 128 + j], r);
    float den = DEN[(size_t)n * 4 + (j >> 5)] + 1e-16f;
    float o = NUM[(size_t)n * 128 + j] / den;
    red[j] = o * Wb[j] + r * Wb[128 + j] + (o - r) * Wb[256 + j];
    __syncthreads();
    for (int s = 64; s > 0; s >>= 1) {
        if (j < s) red[j] += red[j + s];
        __syncthreads();
    }
    float beta = 1.0f / (1.0f + expf(-red[0]));
    A[(size_t)n * 128 + j] = beta * r + (1.0f - beta) * o;
}

// ---------------------------------------------------------------------------
// K5: y = relu(x @ W + b), accumulate per-column sum/sumsq (double atomics).
// thread = (node, col), block covers 8 nodes x 32 cols.
// ---------------------------------------------------------------------------
__global__ void k_linstats(const float* __restrict__ A, const float* __restrict__ W,
                           const float* __restrict__ b, float* __restrict__ Y,
                           double* __restrict__ SUM, double* __restrict__ SUMSQ, int N) {
    int t = blockIdx.x * 256 + threadIdx.x;
    int n = t >> 5, j = t & 31;
    float y = 0.f;
    if (n < N) {
        const float* xr = A + (size_t)n * 128;
        float acc = b[j];
        for (int d = 0; d < 128; d++) acc = fmaf(xr[d], W[d * 32 + j], acc);
        y = fmaxf(acc, 0.f);
        Y[(size_t)n * 32 + j] = y;
    }
    __shared__ float s1[256], s2[256];
    s1[threadIdx.x] = y; s2[threadIdx.x] = y * y;
    __syncthreads();
    for (int s = 128; s >= 32; s >>= 1) {
        if (threadIdx.x < s) { s1[threadIdx.x] += s1[threadIdx.x + s]; s2[threadIdx.x] += s2[threadIdx.x + s]; }
        __syncthreads();
    }
    if (threadIdx.x < 32) {
        atomicAdd(&SUM[threadIdx.x], (double)s1[threadIdx.x]);
        atomicAdd(&SUMSQ[threadIdx.x], (double)s2[threadIdx.x]);
    }
}

// K6: batchnorm apply (in place)
__global__ void k_bnapply(float* __restrict__ Y, const double* __restrict__ SUM,
                          const double* __restrict__ SUMSQ,
                          const float* __restrict__ g, const float* __restrict__ b, int N) {
    int t = blockIdx.x * 256 + threadIdx.x;
    if (t >= N * 32) return;
    int j = t & 31;
    double m = SUM[j] / N;
    double v = SUMSQ[j] / N - m * m;
    float mf = (float)m;
    float inv = rsqrtf((float)v + 1e-5f);
    Y[t] = (Y[t] - mf) * inv * g[j] + b[j];
}

// generic linear (+relu). Dout is power of two; shift = log2(Dout).
__global__ void k_linear(const float* __restrict__ X, const float* __restrict__ W,
                         const float* __restrict__ b, float* __restrict__ Y,
                         int N, int Din, int Dout, int shift, int relu_flag) {
    int t = blockIdx.x * blockDim.x + threadIdx.x;
    if (t >= N * Dout) return;
    int n = t >> shift, j = t & (Dout - 1);
    const float* xr = X + (size_t)n * Din;
    float acc = b[j];
    for (int d = 0; d < Din; d++) acc = fmaf(xr[d], W[d * Dout + j], acc);
    if (relu_flag) acc = fmaxf(acc, 0.f);
    Y[t] = acc;
}

// ---------------------------------------------------------------------------
// Head kernels
// ---------------------------------------------------------------------------
__global__ void k_head1(const float* __restrict__ X3, const float* __restrict__ remW,
                        const float* __restrict__ remB, const int* __restrict__ active,
                        float* __restrict__ l1out, unsigned long long* __restrict__ slot1,
                        unsigned int* __restrict__ m1, int N) {
    int n = blockIdx.x * 256 + threadIdx.x;
    if (n >= N) return;
    const float* xr = X3 + (size_t)n * 64;
    float acc = remB[0];
    for (int d = 0; d < 64; d++) acc = fmaf(xr[d], remW[d], acc);
    float maskf = (active[n] == 1) ? 0.f : NEGF;
    float rm = (n < 15) ? ((maskf == 0.f) ? NEGF : 0.f) : maskf;
    float l1 = acc + rm;
    l1out[n] = l1;
    atomicMax(m1, fmono(l1));
    float z = l1 + gumbel_at(n, 0, N);
    unsigned long long p = ((unsigned long long)fmono(z) << 32) |
                           (unsigned long long)(0xFFFFFFFFu - (unsigned)n);
    atomicMax(slot1, p);
}

__global__ void k_head2(const float* __restrict__ X3, const float* __restrict__ addW,
                        const float* __restrict__ addB,
                        const unsigned long long* __restrict__ slot1,
                        float* __restrict__ tvec, int* __restrict__ a1buf) {
    int j = threadIdx.x;  // 64
    unsigned long long p = *slot1;
    int a1 = (int)(0xFFFFFFFFu - (unsigned)(p & 0xFFFFFFFFull));
    const float* xr = X3 + (size_t)a1 * 64;
    float acc = addB[j];
    for (int d = 0; d < 64; d++) acc = fmaf(xr[d], addW[d * 64 + j], acc);
    tvec[j] = tanhf(acc);
    if (j == 0) *a1buf = a1;
}

__global__ void k_head3(const float* __restrict__ X3, const float* __restrict__ tvec,
                        const int* __restrict__ active, const int* __restrict__ a1buf,
                        float* __restrict__ l2out, unsigned long long* __restrict__ slot2,
                        unsigned int* __restrict__ m2, int N) {
    int n = blockIdx.x * 256 + threadIdx.x;
    if (n >= N) return;
    const float* xr = X3 + (size_t)n * 64;
    float acc = 0.f;
    for (int d = 0; d < 64; d++) acc = fmaf(xr[d], tvec[d], acc);
    float maskf = (active[n] == 1) ? 0.f : NEGF;
    if (n == *a1buf) maskf = 0.f;
    float l2 = acc + maskf;
    l2out[n] = l2;
    atomicMax(m2, fmono(l2));
    float z = l2 + gumbel_at(n, 1, N);
    unsigned long long p = ((unsigned long long)fmono(z) << 32) |
                           (unsigned long long)(0xFFFFFFFFu - (unsigned)n);
    atomicMax(slot2, p);
}

__global__ void k_sumexp(const float* __restrict__ l1, const float* __restrict__ l2,
                         const unsigned int* __restrict__ m1, const unsigned int* __restrict__ m2,
                         float* __restrict__ se, int N) {
    int t = blockIdx.x * 256 + threadIdx.x;
    float M1 = funmono(*m1), M2 = funmono(*m2);
    float e1 = 0.f, e2 = 0.f;
    if (t < N) { e1 = expf(l1[t] - M1); e2 = expf(l2[t] - M2); }
    __shared__ float r1[256], r2[256];
    r1[threadIdx.x] = e1; r2[threadIdx.x] = e2;
    __syncthreads();
    for (int s = 128; s > 0; s >>= 1) {
        if (threadIdx.x < s) { r1[threadIdx.x] += r1[threadIdx.x + s]; r2[threadIdx.x] += r2[threadIdx.x + s]; }
        __syncthreads();
    }
    if (threadIdx.x == 0) { atomicAdd(&se[0], r1[0]); atomicAdd(&se[1], r2[0]); }
}

__global__ void k_final(const float* __restrict__ l1, const float* __restrict__ l2,
                        const unsigned long long* __restrict__ slot2,
                        const int* __restrict__ a1buf,
                        const unsigned int* __restrict__ m1, const unsigned int* __restrict__ m2,
                        const float* __restrict__ se, float* __restrict__ outTail, int N) {
    int a1 = *a1buf;
    int a2 = (int)(0xFFFFFFFFu - (unsigned)((*slot2) & 0xFFFFFFFFull));
    outTail[0] = (float)a1;
    outTail[1] = (float)a2;
    outTail[2] = l1[a1] - (funmono(*m1) + logf(se[0]));
    outTail[3] = l2[a2] - (funmono(*m2) + logf(se[1]));
}

// ---------------------------------------------------------------------------
// Host launcher
// ---------------------------------------------------------------------------
extern "C" void kernel_launch(void* const* d_in, const int* in_sizes, int n_in,
                              void* d_out, int out_size, void* d_ws, size_t ws_size,
                              hipStream_t stream) {
    const float* node_type = (const float*)d_in[0];
    const float* requests  = (const float*)d_in[1];
    const float* latency   = (const float*)d_in[2];
    const int* edge_index  = (const int*)d_in[3];
    const int* active      = (const int*)d_in[4];
    int N = in_sizes[0];
    int E = in_sizes[2];
    const int* src = edge_index;
    const int* dst = edge_index + E;
    float* out = (float*)d_out;

    // workspace layout
    char* base = (char*)d_ws;
    size_t off = 0;
    auto alloc = [&](size_t bytes) -> char* {
        char* p = base + off;
        off += (bytes + 255) & ~(size_t)255;
        return p;
    };
    float* A     = (float*)alloc((size_t)N * 128 * 4);
    float* Q     = (float*)alloc((size_t)N * 128 * 4);  // reused as NUM, then emb y1
    float* Kb    = (float*)alloc((size_t)N * 128 * 4);  // reused as emb y2
    float* Vb    = (float*)alloc((size_t)N * 128 * 4);  // reused as emb y3 (x3)
    float* H32   = (float*)alloc((size_t)N * 32 * 4);
    float* ALPHA = (float*)alloc((size_t)E * 4 * 4);
    unsigned int* AMAXU = (unsigned int*)alloc((size_t)N * 4 * 4 * 2);  // AMAX + DEN
    float* DEN   = (float*)(AMAXU + (size_t)N * 4);
    double* SUM  = (double*)alloc(512);
    double* SUMSQ = SUM + 32;
    char* small  = alloc(1024);
    unsigned long long* slot1 = (unsigned long long*)small;
    unsigned long long* slot2 = slot1 + 1;
    unsigned int* m1 = (unsigned int*)(small + 16);
    unsigned int* m2 = m1 + 1;
    float* se = (float*)(small + 24);
    int* a1buf = (int*)(small + 32);
    float* tvec = (float*)(small + 64);

    int eg = (E * 4 + 255) / 256;
    int ng = (N + 255) / 256;
    int n32g = (N * 32 + 255) / 256;

    for (int L = 0; L < 5; ++L) {
        int din = L ? 32 : 2;
        const float* xin = L ? H32 : nullptr;
        const float* Wq = L ? (const float*)d_in[19] + (size_t)(L - 1) * 4096 : (const float*)d_in[5];
        const float* bq = L ? (const float*)d_in[20] + (size_t)(L - 1) * 128  : (const float*)d_in[6];
        const float* Wk = L ? (const float*)d_in[21] + (size_t)(L - 1) * 4096 : (const float*)d_in[7];
        const float* bk = L ? (const float*)d_in[22] + (size_t)(L - 1) * 128  : (const float*)d_in[8];
        const float* Wv = L ? (const float*)d_in[23] + (size_t)(L - 1) * 4096 : (const float*)d_in[9];
        const float* bv = L ? (const float*)d_in[24] + (size_t)(L - 1) * 128  : (const float*)d_in[10];
        const float* We = L ? (const float*)d_in[25] + (size_t)(L - 1) * 128  : (const float*)d_in[11];
        const float* Ws = L ? (const float*)d_in[26] + (size_t)(L - 1) * 4096 : (const float*)d_in[12];
        const float* bs = L ? (const float*)d_in[27] + (size_t)(L - 1) * 128  : (const float*)d_in[13];
        const float* Wb = L ? (const float*)d_in[28] + (size_t)(L - 1) * 384  : (const float*)d_in[14];
        const float* tW = L ? (const float*)d_in[29] + (size_t)(L - 1) * 4096 : (const float*)d_in[15];
        const float* tb = L ? (const float*)d_in[30] + (size_t)(L - 1) * 32   : (const float*)d_in[16];
        const float* bg = L ? (const float*)d_in[31] + (size_t)(L - 1) * 32   : (const float*)d_in[17];
        const float* bb = L ? (const float*)d_in[32] + (size_t)(L - 1) * 32   : (const float*)d_in[18];

        (void)hipMemsetAsync(AMAXU, 0, (size_t)N * 32, stream);  // AMAX + DEN
        k_qkv<<<N, 128, 0, stream>>>(xin, node_type, requests, din, N,
                                     Wq, bq, Wk, bk, Wv, bv, Q, Kb, Vb);
        k_alpha<<<eg, 256, 0, stream>>>(src, dst, latency, Q, Kb, We, ALPHA, AMAXU, E);
        (void)hipMemsetAsync(Q, 0, (size_t)N * 512, stream);  // NUM = Q
        k_accum<<<eg, 256, 0, stream>>>(src, dst, latency, Vb, We, ALPHA, AMAXU, Q, DEN, E);
        k_combine<<<N, 128, 0, stream>>>(xin, node_type, requests, din, N,
                                         Ws, bs, Wb, Q, DEN, A);
        (void)hipMemsetAsync(SUM, 0, 512, stream);
        k_linstats<<<n32g, 256, 0, stream>>>(A, tW, tb, H32, SUM, SUMSQ, N);
        k_bnapply<<<n32g, 256, 0, stream>>>(H32, SUM, SUMSQ, bg, bb, N);
    }

    // embedding MLP: 32 -> 128 -> 64 -> 64
    k_linear<<<(N * 128 + 255) / 256, 256, 0, stream>>>(
        H32, (const float*)d_in[33], (const float*)d_in[34], Q, N, 32, 128, 7, 1);
    k_linear<<<(N * 64 + 255) / 256, 256, 0, stream>>>(
        Q, (const float*)d_in[35], (const float*)d_in[36], Kb, N, 128, 64, 6, 1);
    k_linear<<<(N * 64 + 255) / 256, 256, 0, stream>>>(
        Kb, (const float*)d_in[37], (const float*)d_in[38], Vb, N, 64, 64, 6, 0);

    // head
    (void)hipMemsetAsync(small, 0, 64, stream);
    k_head1<<<ng, 256, 0, stream>>>(Vb, (const float*)d_in[39], (const float*)d_in[40],
                                    active, out, slot1, m1, N);
    k_head2<<<1, 64, 0, stream>>>(Vb, (const float*)d_in[41], (const float*)d_in[42],
                                  slot1, tvec, a1buf);
    k_head3<<<ng, 256, 0, stream>>>(Vb, tvec, active, a1buf, out + N, slot2, m2, N);
    k_sumexp<<<ng, 256, 0, stream>>>(out, out + N, m1, m2, se, N);
    k_final<<<1, 1, 0, stream>>>(out, out + N, slot2, a1buf, m1, m2, se, out + 2 * N, N);
}

// Round 3
// 2512.698 us; speedup vs baseline: 6.3855x; 6.3855x over previous
//
#include <hip/hip_runtime.h>
#include <cstdint>
#include <math.h>

// ---------------------------------------------------------------------------
// Threefry-2x32-20, exactly as JAX lowers it.
// ---------------------------------------------------------------------------
__device__ __forceinline__ uint32_t rotl32(uint32_t x, uint32_t n) {
    return (x << n) | (x >> (32u - n));
}

__device__ __forceinline__ void tf2x32(uint32_t k0, uint32_t k1,
                                       uint32_t x0, uint32_t x1,
                                       uint32_t& o0, uint32_t& o1) {
    uint32_t k2 = k0 ^ k1 ^ 0x1BD11BDAu;
    x0 += k0; x1 += k1;
    x0 += x1; x1 = rotl32(x1, 13); x1 ^= x0;
    x0 += x1; x1 = rotl32(x1, 15); x1 ^= x0;
    x0 += x1; x1 = rotl32(x1, 26); x1 ^= x0;
    x0 += x1; x1 = rotl32(x1, 6);  x1 ^= x0;
    x0 += k1; x1 += k2 + 1u;
    x0 += x1; x1 = rotl32(x1, 17); x1 ^= x0;
    x0 += x1; x1 = rotl32(x1, 29); x1 ^= x0;
    x0 += x1; x1 = rotl32(x1, 16); x1 ^= x0;
    x0 += x1; x1 = rotl32(x1, 24); x1 ^= x0;
    x0 += k2; x1 += k0 + 2u;
    x0 += x1; x1 = rotl32(x1, 13); x1 ^= x0;
    x0 += x1; x1 = rotl32(x1, 15); x1 ^= x0;
    x0 += x1; x1 = rotl32(x1, 26); x1 ^= x0;
    x0 += x1; x1 = rotl32(x1, 6);  x1 ^= x0;
    x0 += k0; x1 += k1 + 3u;
    x0 += x1; x1 = rotl32(x1, 17); x1 ^= x0;
    x0 += x1; x1 = rotl32(x1, 29); x1 ^= x0;
    x0 += x1; x1 = rotl32(x1, 16); x1 ^= x0;
    x0 += x1; x1 = rotl32(x1, 24); x1 ^= x0;
    x0 += k1; x1 += k2 + 4u;
    x0 += x1; x1 = rotl32(x1, 13); x1 ^= x0;
    x0 += x1; x1 = rotl32(x1, 15); x1 ^= x0;
    x0 += x1; x1 = rotl32(x1, 26); x1 ^= x0;
    x0 += x1; x1 = rotl32(x1, 6);  x1 ^= x0;
    x0 += k2; x1 += k0 + 5u;
    o0 = x0; o1 = x1;
}

__device__ float gumbel_at(int n, int which, int N) {
    uint32_t a0, a1, b0, b1;
    tf2x32(0u, 42u, 0u, 2u, a0, a1);
    tf2x32(0u, 42u, 1u, 3u, b0, b1);
    uint32_t gk0 = which ? a1 : a0;
    uint32_t gk1 = which ? b1 : b0;
    int half = N >> 1;
    uint32_t o0, o1, bits;
    if (n < half) { tf2x32(gk0, gk1, (uint32_t)n, (uint32_t)(n + half), o0, o1); bits = o0; }
    else          { tf2x32(gk0, gk1, (uint32_t)(n - half), (uint32_t)n, o0, o1); bits = o1; }
    float f = __uint_as_float((bits >> 9) | 0x3F800000u) - 1.0f;
    float u = fmaxf(1.17549435e-38f, f);
    return -logf(-logf(u));
}

__device__ __forceinline__ uint32_t fmono(float f) {
    uint32_t b = __float_as_uint(f);
    return (b & 0x80000000u) ? ~b : (b | 0x80000000u);
}
__device__ __forceinline__ float funmono(uint32_t u) {
    uint32_t b = (u & 0x80000000u) ? (u & 0x7FFFFFFFu) : ~u;
    return __uint_as_float(b);
}

#define NEGF (-1e9f)
#define CAP 64

// ---------------------------------------------------------------------------
// CSR build: histogram, 3-kernel exclusive scan, atomic-cursor fill.
// ---------------------------------------------------------------------------
__global__ void k_hist(const int* __restrict__ dstp, int* __restrict__ deg, int E) {
    int e = blockIdx.x * 256 + threadIdx.x;
    if (e < E) atomicAdd(&deg[dstp[e]], 1);
}

__global__ void k_scan1(const int* __restrict__ deg, int* __restrict__ bsum, int N) {
    __shared__ int s[256];
    int i = blockIdx.x * 256 + threadIdx.x;
    s[threadIdx.x] = (i < N) ? deg[i] : 0;
    __syncthreads();
    for (int st = 128; st > 0; st >>= 1) {
        if (threadIdx.x < st) s[threadIdx.x] += s[threadIdx.x + st];
        __syncthreads();
    }
    if (threadIdx.x == 0) bsum[blockIdx.x] = s[0];
}

__global__ void k_scan2(int* __restrict__ bsum, int nb) {
    __shared__ int s[256];
    int i = threadIdx.x;
    int v = (i < nb) ? bsum[i] : 0;
    s[i] = v;
    __syncthreads();
    for (int st = 1; st < 256; st <<= 1) {
        int t = (i >= st) ? s[i - st] : 0;
        __syncthreads();
        s[i] += t;
        __syncthreads();
    }
    if (i < nb) bsum[i] = s[i] - v;  // exclusive
}

__global__ void k_scan3(const int* __restrict__ deg, const int* __restrict__ bsum,
                        int* __restrict__ rowptr, int* __restrict__ cursor, int N) {
    __shared__ int s[256];
    int i = blockIdx.x * 256 + threadIdx.x;
    int v = (i < N) ? deg[i] : 0;
    s[threadIdx.x] = v;
    __syncthreads();
    for (int st = 1; st < 256; st <<= 1) {
        int t = (threadIdx.x >= st) ? s[threadIdx.x - st] : 0;
        __syncthreads();
        s[threadIdx.x] += t;
        __syncthreads();
    }
    int excl = s[threadIdx.x] - v + bsum[blockIdx.x];
    if (i < N) { rowptr[i] = excl; cursor[i] = excl; }
}

__global__ void k_fill(const int* __restrict__ dstp, int* __restrict__ cursor,
                       int* __restrict__ eidx, int E) {
    int e = blockIdx.x * 256 + threadIdx.x;
    if (e < E) {
        int pos = atomicAdd(&cursor[dstp[e]], 1);
        eidx[pos] = e;
    }
}

// ---------------------------------------------------------------------------
// K1: q/k/v projections. One block per node, 128 threads.
// ---------------------------------------------------------------------------
__global__ void k_qkv(const float* __restrict__ xin, const float* __restrict__ nt,
                      const float* __restrict__ rq, int din, int N,
                      const float* __restrict__ Wq, const float* __restrict__ bq,
                      const float* __restrict__ Wk, const float* __restrict__ bk,
                      const float* __restrict__ Wv, const float* __restrict__ bv,
                      float* __restrict__ Q, float* __restrict__ K, float* __restrict__ V) {
    int n = blockIdx.x;
    int j = threadIdx.x;
    __shared__ float xs[32];
    if (j < din) xs[j] = (din == 2) ? (j == 0 ? nt[n] : rq[n]) : xin[(size_t)n * din + j];
    __syncthreads();
    float q = bq[j], k = bk[j], v = bv[j];
    for (int d = 0; d < din; d++) {
        float x = xs[d];
        q = fmaf(x, Wq[d * 128 + j], q);
        k = fmaf(x, Wk[d * 128 + j], k);
        v = fmaf(x, Wv[d * 128 + j], v);
    }
    size_t o = (size_t)n * 128 + j;
    Q[o] = q; K[o] = k; V[o] = v;
}

// ---------------------------------------------------------------------------
// Fused per-node attention + gate. One block per dst node, 128 threads.
// thread j: head h=j>>5, channel c=j&31. CSR gather, no atomics.
// ---------------------------------------------------------------------------
__global__ void k_attn(const float* __restrict__ xin, const float* __restrict__ nt,
                       const float* __restrict__ rq, int din,
                       const int* __restrict__ srcp, const float* __restrict__ lat,
                       const float* __restrict__ Q, const float* __restrict__ Kb,
                       const float* __restrict__ Vb, const float* __restrict__ We,
                       const float* __restrict__ Ws, const float* __restrict__ bs,
                       const float* __restrict__ Wb,
                       const int* __restrict__ rowptr, const int* __restrict__ deg,
                       const int* __restrict__ eidx,
                       float* __restrict__ A) {
    int n = blockIdx.x;
    int j = threadIdx.x;
    int h = j >> 5, lane = j & 31;
    __shared__ float xs[32];
    __shared__ float salpha[4 * CAP];
    __shared__ float red[128];
    if (j < din) xs[j] = (din == 2) ? (j == 0 ? nt[n] : rq[n]) : xin[(size_t)n * din + j];

    float qj = Q[(size_t)n * 128 + j];
    float wej = We[j];
    int start = rowptr[n], d = deg[n];

    // pass 1: alphas + max
    float amax = -INFINITY;
    for (int idx = 0; idx < d; ++idx) {
        int e = eidx[start + idx];
        int s = srcp[e];
        float l = lat[e];
        float kk = Kb[(size_t)s * 128 + j];
        float t = qj * fmaf(l, wej, kk);
        t += __shfl_xor(t, 1); t += __shfl_xor(t, 2); t += __shfl_xor(t, 4);
        t += __shfl_xor(t, 8); t += __shfl_xor(t, 16);
        float alpha = t * 0.17677669529663687f;
        if (lane == 0 && idx < CAP) salpha[h * CAP + idx] = alpha;
        amax = fmaxf(amax, alpha);
    }
    __syncthreads();

    // pass 2: softmax-weighted V accumulation
    float den = 0.f, num = 0.f;
    for (int idx = 0; idx < d; ++idx) {
        int e = eidx[start + idx];
        int s = srcp[e];
        float l = lat[e];
        float alpha;
        if (idx < CAP) {
            alpha = salpha[h * CAP + idx];
        } else {
            float kk = Kb[(size_t)s * 128 + j];
            float t = qj * fmaf(l, wej, kk);
            t += __shfl_xor(t, 1); t += __shfl_xor(t, 2); t += __shfl_xor(t, 4);
            t += __shfl_xor(t, 8); t += __shfl_xor(t, 16);
            alpha = t * 0.17677669529663687f;
        }
        float w = expf(alpha - amax);
        den += w;
        float v = Vb[(size_t)s * 128 + j];
        num = fmaf(fmaf(l, wej, v), w, num);
    }
    float o = num / (den + 1e-16f);

    // gate: xr = x@Ws+bs; beta = sigmoid([o, r, o-r]@Wb)
    float r = bs[j];
    for (int dd = 0; dd < din; ++dd) r = fmaf(xs[dd], Ws[dd * 128 + j], r);
    red[j] = o * Wb[j] + r * Wb[128 + j] + (o - r) * Wb[256 + j];
    __syncthreads();
    for (int st = 64; st > 0; st >>= 1) {
        if (j < st) red[j] += red[j + st];
        __syncthreads();
    }
    float beta = 1.0f / (1.0f + expf(-red[0]));
    A[(size_t)n * 128 + j] = beta * r + (1.0f - beta) * o;
}

// ---------------------------------------------------------------------------
// K5: y = relu(x @ W + b) + per-column sum/sumsq (double atomics).
// ---------------------------------------------------------------------------
__global__ void k_linstats(const float* __restrict__ A, const float* __restrict__ W,
                           const float* __restrict__ b, float* __restrict__ Y,
                           double* __restrict__ SUM, double* __restrict__ SUMSQ, int N) {
    int t = blockIdx.x * 256 + threadIdx.x;
    int n = t >> 5, j = t & 31;
    float y = 0.f;
    if (n < N) {
        const float* xr = A + (size_t)n * 128;
        float acc = b[j];
        for (int d = 0; d < 128; d++) acc = fmaf(xr[d], W[d * 32 + j], acc);
        y = fmaxf(acc, 0.f);
        Y[(size_t)n * 32 + j] = y;
    }
    __shared__ float s1[256], s2[256];
    s1[threadIdx.x] = y; s2[threadIdx.x] = y * y;
    __syncthreads();
    for (int s = 128; s >= 32; s >>= 1) {
        if (threadIdx.x < s) { s1[threadIdx.x] += s1[threadIdx.x + s]; s2[threadIdx.x] += s2[threadIdx.x + s]; }
        __syncthreads();
    }
    if (threadIdx.x < 32) {
        atomicAdd(&SUM[threadIdx.x], (double)s1[threadIdx.x]);
        atomicAdd(&SUMSQ[threadIdx.x], (double)s2[threadIdx.x]);
    }
}

__global__ void k_bnapply(float* __restrict__ Y, const double* __restrict__ SUM,
                          const double* __restrict__ SUMSQ,
                          const float* __restrict__ g, const float* __restrict__ b, int N) {
    int t = blockIdx.x * 256 + threadIdx.x;
    if (t >= N * 32) return;
    int j = t & 31;
    double m = SUM[j] / N;
    double v = SUMSQ[j] / N - m * m;
    float mf = (float)m;
    float inv = rsqrtf((float)v + 1e-5f);
    Y[t] = (Y[t] - mf) * inv * g[j] + b[j];
}

__global__ void k_linear(const float* __restrict__ X, const float* __restrict__ W,
                         const float* __restrict__ b, float* __restrict__ Y,
                         int N, int Din, int Dout, int shift, int relu_flag) {
    int t = blockIdx.x * blockDim.x + threadIdx.x;
    if (t >= N * Dout) return;
    int n = t >> shift, j = t & (Dout - 1);
    const float* xr = X + (size_t)n * Din;
    float acc = b[j];
    for (int d = 0; d < Din; d++) acc = fmaf(xr[d], W[d * Dout + j], acc);
    if (relu_flag) acc = fmaxf(acc, 0.f);
    Y[t] = acc;
}

// ---------------------------------------------------------------------------
// Head kernels
// ---------------------------------------------------------------------------
__global__ void k_head1(const float* __restrict__ X3, const float* __restrict__ remW,
                        const float* __restrict__ remB, const int* __restrict__ active,
                        float* __restrict__ l1out, unsigned long long* __restrict__ slot1,
                        unsigned int* __restrict__ m1, int N) {
    int n = blockIdx.x * 256 + threadIdx.x;
    if (n >= N) return;
    const float* xr = X3 + (size_t)n * 64;
    float acc = remB[0];
    for (int d = 0; d < 64; d++) acc = fmaf(xr[d], remW[d], acc);
    float maskf = (active[n] == 1) ? 0.f : NEGF;
    float rm = (n < 15) ? ((maskf == 0.f) ? NEGF : 0.f) : maskf;
    float l1 = acc + rm;
    l1out[n] = l1;
    atomicMax(m1, fmono(l1));
    float z = l1 + gumbel_at(n, 0, N);
    unsigned long long p = ((unsigned long long)fmono(z) << 32) |
                           (unsigned long long)(0xFFFFFFFFu - (unsigned)n);
    atomicMax(slot1, p);
}

__global__ void k_head2(const float* __restrict__ X3, const float* __restrict__ addW,
                        const float* __restrict__ addB,
                        const unsigned long long* __restrict__ slot1,
                        float* __restrict__ tvec, int* __restrict__ a1buf) {
    int j = threadIdx.x;  // 64
    unsigned long long p = *slot1;
    int a1 = (int)(0xFFFFFFFFu - (unsigned)(p & 0xFFFFFFFFull));
    const float* xr = X3 + (size_t)a1 * 64;
    float acc = addB[j];
    for (int d = 0; d < 64; d++) acc = fmaf(xr[d], addW[d * 64 + j], acc);
    tvec[j] = tanhf(acc);
    if (j == 0) *a1buf = a1;
}

__global__ void k_head3(const float* __restrict__ X3, const float* __restrict__ tvec,
                        const int* __restrict__ active, const int* __restrict__ a1buf,
                        float* __restrict__ l2out, unsigned long long* __restrict__ slot2,
                        unsigned int* __restrict__ m2, int N) {
    int n = blockIdx.x * 256 + threadIdx.x;
    if (n >= N) return;
    const float* xr = X3 + (size_t)n * 64;
    float acc = 0.f;
    for (int d = 0; d < 64; d++) acc = fmaf(xr[d], tvec[d], acc);
    float maskf = (active[n] == 1) ? 0.f : NEGF;
    if (n == *a1buf) maskf = 0.f;
    float l2 = acc + maskf;
    l2out[n] = l2;
    atomicMax(m2, fmono(l2));
    float z = l2 + gumbel_at(n, 1, N);
    unsigned long long p = ((unsigned long long)fmono(z) << 32) |
                           (unsigned long long)(0xFFFFFFFFu - (unsigned)n);
    atomicMax(slot2, p);
}

__global__ void k_sumexp(const float* __restrict__ l1, const float* __restrict__ l2,
                         const unsigned int* __restrict__ m1, const unsigned int* __restrict__ m2,
                         float* __restrict__ se, int N) {
    int t = blockIdx.x * 256 + threadIdx.x;
    float M1 = funmono(*m1), M2 = funmono(*m2);
    float e1 = 0.f, e2 = 0.f;
    if (t < N) { e1 = expf(l1[t] - M1); e2 = expf(l2[t] - M2); }
    __shared__ float r1[256], r2[256];
    r1[threadIdx.x] = e1; r2[threadIdx.x] = e2;
    __syncthreads();
    for (int s = 128; s > 0; s >>= 1) {
        if (threadIdx.x < s) { r1[threadIdx.x] += r1[threadIdx.x + s]; r2[threadIdx.x] += r2[threadIdx.x + s]; }
        __syncthreads();
    }
    if (threadIdx.x == 0) { atomicAdd(&se[0], r1[0]); atomicAdd(&se[1], r2[0]); }
}

__global__ void k_final(const float* __restrict__ l1, const float* __restrict__ l2,
                        const unsigned long long* __restrict__ slot2,
                        const int* __restrict__ a1buf,
                        const unsigned int* __restrict__ m1, const unsigned int* __restrict__ m2,
                        const float* __restrict__ se, float* __restrict__ outTail, int N) {
    int a1 = *a1buf;
    int a2 = (int)(0xFFFFFFFFu - (unsigned)((*slot2) & 0xFFFFFFFFull));
    outTail[0] = (float)a1;
    outTail[1] = (float)a2;
    outTail[2] = l1[a1] - (funmono(*m1) + logf(se[0]));
    outTail[3] = l2[a2] - (funmono(*m2) + logf(se[1]));
}

// ---------------------------------------------------------------------------
// Host launcher
// ---------------------------------------------------------------------------
extern "C" void kernel_launch(void* const* d_in, const int* in_sizes, int n_in,
                              void* d_out, int out_size, void* d_ws, size_t ws_size,
                              hipStream_t stream) {
    const float* node_type = (const float*)d_in[0];
    const float* requests  = (const float*)d_in[1];
    const float* latency   = (const float*)d_in[2];
    const int* edge_index  = (const int*)d_in[3];
    const int* active      = (const int*)d_in[4];
    int N = in_sizes[0];
    int E = in_sizes[2];
    const int* src = edge_index;
    const int* dst = edge_index + E;
    float* out = (float*)d_out;

    // workspace layout
    char* base = (char*)d_ws;
    size_t off = 0;
    auto alloc = [&](size_t bytes) -> char* {
        char* p = base + off;
        off += (bytes + 255) & ~(size_t)255;
        return p;
    };
    float* A     = (float*)alloc((size_t)N * 128 * 4);
    float* Q     = (float*)alloc((size_t)N * 128 * 4);  // later emb y1
    float* Kb    = (float*)alloc((size_t)N * 128 * 4);  // later emb y2
    float* Vb    = (float*)alloc((size_t)N * 128 * 4);  // later emb y3 (x3)
    float* H32   = (float*)alloc((size_t)N * 32 * 4);
    int* deg     = (int*)alloc((size_t)N * 4);
    int* rowptr  = (int*)alloc((size_t)N * 4);
    int* cursor  = (int*)alloc((size_t)N * 4);
    int* eidx    = (int*)alloc((size_t)E * 4);
    int* bsum    = (int*)alloc(1024 * 4);
    double* SUM  = (double*)alloc(512);
    double* SUMSQ = SUM + 32;
    char* small  = alloc(1024);
    unsigned long long* slot1 = (unsigned long long*)small;
    unsigned long long* slot2 = slot1 + 1;
    unsigned int* m1 = (unsigned int*)(small + 16);
    unsigned int* m2 = m1 + 1;
    float* se = (float*)(small + 24);
    int* a1buf = (int*)(small + 32);
    float* tvec = (float*)(small + 64);

    int ng = (N + 255) / 256;
    int egE = (E + 255) / 256;
    int n32g = (N * 32 + 255) / 256;
    int nb = ng;  // number of 256-blocks over N (196 for N=50000)

    // ---- CSR build (per call; d_ws is re-poisoned before every launch) ----
    (void)hipMemsetAsync(deg, 0, (size_t)N * 4, stream);
    k_hist<<<egE, 256, 0, stream>>>(dst, deg, E);
    k_scan1<<<nb, 256, 0, stream>>>(deg, bsum, N);
    k_scan2<<<1, 256, 0, stream>>>(bsum, nb);
    k_scan3<<<nb, 256, 0, stream>>>(deg, bsum, rowptr, cursor, N);
    k_fill<<<egE, 256, 0, stream>>>(dst, cursor, eidx, E);

    for (int L = 0; L < 5; ++L) {
        int din = L ? 32 : 2;
        const float* xin = L ? H32 : nullptr;
        const float* Wq = L ? (const float*)d_in[19] + (size_t)(L - 1) * 4096 : (const float*)d_in[5];
        const float* bq = L ? (const float*)d_in[20] + (size_t)(L - 1) * 128  : (const float*)d_in[6];
        const float* Wk = L ? (const float*)d_in[21] + (size_t)(L - 1) * 4096 : (const float*)d_in[7];
        const float* bk = L ? (const float*)d_in[22] + (size_t)(L - 1) * 128  : (const float*)d_in[8];
        const float* Wv = L ? (const float*)d_in[23] + (size_t)(L - 1) * 4096 : (const float*)d_in[9];
        const float* bv = L ? (const float*)d_in[24] + (size_t)(L - 1) * 128  : (const float*)d_in[10];
        const float* We = L ? (const float*)d_in[25] + (size_t)(L - 1) * 128  : (const float*)d_in[11];
        const float* Ws = L ? (const float*)d_in[26] + (size_t)(L - 1) * 4096 : (const float*)d_in[12];
        const float* bs = L ? (const float*)d_in[27] + (size_t)(L - 1) * 128  : (const float*)d_in[13];
        const float* Wb = L ? (const float*)d_in[28] + (size_t)(L - 1) * 384  : (const float*)d_in[14];
        const float* tW = L ? (const float*)d_in[29] + (size_t)(L - 1) * 4096 : (const float*)d_in[15];
        const float* tb = L ? (const float*)d_in[30] + (size_t)(L - 1) * 32   : (const float*)d_in[16];
        const float* bg = L ? (const float*)d_in[31] + (size_t)(L - 1) * 32   : (const float*)d_in[17];
        const float* bb = L ? (const float*)d_in[32] + (size_t)(L - 1) * 32   : (const float*)d_in[18];

        k_qkv<<<N, 128, 0, stream>>>(xin, node_type, requests, din, N,
                                     Wq, bq, Wk, bk, Wv, bv, Q, Kb, Vb);
        k_attn<<<N, 128, 0, stream>>>(xin, node_type, requests, din,
                                      src, latency, Q, Kb, Vb, We, Ws, bs, Wb,
                                      rowptr, deg, eidx, A);
        (void)hipMemsetAsync(SUM, 0, 512, stream);
        k_linstats<<<n32g, 256, 0, stream>>>(A, tW, tb, H32, SUM, SUMSQ, N);
        k_bnapply<<<n32g, 256, 0, stream>>>(H32, SUM, SUMSQ, bg, bb, N);
    }

    // embedding MLP: 32 -> 128 -> 64 -> 64
    k_linear<<<(N * 128 + 255) / 256, 256, 0, stream>>>(
        H32, (const float*)d_in[33], (const float*)d_in[34], Q, N, 32, 128, 7, 1);
    k_linear<<<(N * 64 + 255) / 256, 256, 0, stream>>>(
        Q, (const float*)d_in[35], (const float*)d_in[36], Kb, N, 128, 64, 6, 1);
    k_linear<<<(N * 64 + 255) / 256, 256, 0, stream>>>(
        Kb, (const float*)d_in[37], (const float*)d_in[38], Vb, N, 64, 64, 6, 0);

    // head
    (void)hipMemsetAsync(small, 0, 64, stream);
    k_head1<<<ng, 256, 0, stream>>>(Vb, (const float*)d_in[39], (const float*)d_in[40],
                                    active, out, slot1, m1, N);
    k_head2<<<1, 64, 0, stream>>>(Vb, (const float*)d_in[41], (const float*)d_in[42],
                                  slot1, tvec, a1buf);
    k_head3<<<ng, 256, 0, stream>>>(Vb, tvec, active, a1buf, out + N, slot2, m2, N);
    k_sumexp<<<ng, 256, 0, stream>>>(out, out + N, m1, m2, se, N);
    k_final<<<1, 1, 0, stream>>>(out, out + N, slot2, a1buf, m1, m2, se, out + 2 * N, N);
}

// Round 4
// 1868.708 us; speedup vs baseline: 8.5860x; 1.3446x over previous
//
#include <hip/hip_runtime.h>
#include <cstdint>
#include <math.h>

// ---------------------------------------------------------------------------
// Threefry-2x32-20, exactly as JAX lowers it.
// ---------------------------------------------------------------------------
__device__ __forceinline__ uint32_t rotl32(uint32_t x, uint32_t n) {
    return (x << n) | (x >> (32u - n));
}

__device__ __forceinline__ void tf2x32(uint32_t k0, uint32_t k1,
                                       uint32_t x0, uint32_t x1,
                                       uint32_t& o0, uint32_t& o1) {
    uint32_t k2 = k0 ^ k1 ^ 0x1BD11BDAu;
    x0 += k0; x1 += k1;
    x0 += x1; x1 = rotl32(x1, 13); x1 ^= x0;
    x0 += x1; x1 = rotl32(x1, 15); x1 ^= x0;
    x0 += x1; x1 = rotl32(x1, 26); x1 ^= x0;
    x0 += x1; x1 = rotl32(x1, 6);  x1 ^= x0;
    x0 += k1; x1 += k2 + 1u;
    x0 += x1; x1 = rotl32(x1, 17); x1 ^= x0;
    x0 += x1; x1 = rotl32(x1, 29); x1 ^= x0;
    x0 += x1; x1 = rotl32(x1, 16); x1 ^= x0;
    x0 += x1; x1 = rotl32(x1, 24); x1 ^= x0;
    x0 += k2; x1 += k0 + 2u;
    x0 += x1; x1 = rotl32(x1, 13); x1 ^= x0;
    x0 += x1; x1 = rotl32(x1, 15); x1 ^= x0;
    x0 += x1; x1 = rotl32(x1, 26); x1 ^= x0;
    x0 += x1; x1 = rotl32(x1, 6);  x1 ^= x0;
    x0 += k0; x1 += k1 + 3u;
    x0 += x1; x1 = rotl32(x1, 17); x1 ^= x0;
    x0 += x1; x1 = rotl32(x1, 29); x1 ^= x0;
    x0 += x1; x1 = rotl32(x1, 16); x1 ^= x0;
    x0 += x1; x1 = rotl32(x1, 24); x1 ^= x0;
    x0 += k1; x1 += k2 + 4u;
    x0 += x1; x1 = rotl32(x1, 13); x1 ^= x0;
    x0 += x1; x1 = rotl32(x1, 15); x1 ^= x0;
    x0 += x1; x1 = rotl32(x1, 26); x1 ^= x0;
    x0 += x1; x1 = rotl32(x1, 6);  x1 ^= x0;
    x0 += k2; x1 += k0 + 5u;
    o0 = x0; o1 = x1;
}

__device__ float gumbel_at(int n, int which, int N) {
    uint32_t a0, a1, b0, b1;
    tf2x32(0u, 42u, 0u, 2u, a0, a1);
    tf2x32(0u, 42u, 1u, 3u, b0, b1);
    uint32_t gk0 = which ? a1 : a0;
    uint32_t gk1 = which ? b1 : b0;
    int half = N >> 1;
    uint32_t o0, o1, bits;
    if (n < half) { tf2x32(gk0, gk1, (uint32_t)n, (uint32_t)(n + half), o0, o1); bits = o0; }
    else          { tf2x32(gk0, gk1, (uint32_t)(n - half), (uint32_t)n, o0, o1); bits = o1; }
    float f = __uint_as_float((bits >> 9) | 0x3F800000u) - 1.0f;
    float u = fmaxf(1.17549435e-38f, f);
    return -logf(-logf(u));
}

__device__ __forceinline__ uint32_t fmono(float f) {
    uint32_t b = __float_as_uint(f);
    return (b & 0x80000000u) ? ~b : (b | 0x80000000u);
}
__device__ __forceinline__ float funmono(uint32_t u) {
    uint32_t b = (u & 0x80000000u) ? (u & 0x7FFFFFFFu) : ~u;
    return __uint_as_float(b);
}

#define NEGF (-1e9f)

// ---------------------------------------------------------------------------
// CSR build: histogram, 3-kernel exclusive scan, atomic-cursor fill.
// ---------------------------------------------------------------------------
__global__ void k_hist(const int* __restrict__ dstp, int* __restrict__ deg, int E) {
    int e = blockIdx.x * 256 + threadIdx.x;
    if (e < E) atomicAdd(&deg[dstp[e]], 1);
}

__global__ void k_scan1(const int* __restrict__ deg, int* __restrict__ bsum, int N) {
    __shared__ int s[256];
    int i = blockIdx.x * 256 + threadIdx.x;
    s[threadIdx.x] = (i < N) ? deg[i] : 0;
    __syncthreads();
    for (int st = 128; st > 0; st >>= 1) {
        if (threadIdx.x < st) s[threadIdx.x] += s[threadIdx.x + st];
        __syncthreads();
    }
    if (threadIdx.x == 0) bsum[blockIdx.x] = s[0];
}

__global__ void k_scan2(int* __restrict__ bsum, int nb) {
    __shared__ int s[256];
    int i = threadIdx.x;
    int v = (i < nb) ? bsum[i] : 0;
    s[i] = v;
    __syncthreads();
    for (int st = 1; st < 256; st <<= 1) {
        int t = (i >= st) ? s[i - st] : 0;
        __syncthreads();
        s[i] += t;
        __syncthreads();
    }
    if (i < nb) bsum[i] = s[i] - v;  // exclusive
}

__global__ void k_scan3(const int* __restrict__ deg, const int* __restrict__ bsum,
                        int* __restrict__ rowptr, int* __restrict__ cursor, int N) {
    __shared__ int s[256];
    int i = blockIdx.x * 256 + threadIdx.x;
    int v = (i < N) ? deg[i] : 0;
    s[threadIdx.x] = v;
    __syncthreads();
    for (int st = 1; st < 256; st <<= 1) {
        int t = (threadIdx.x >= st) ? s[threadIdx.x - st] : 0;
        __syncthreads();
        s[threadIdx.x] += t;
        __syncthreads();
    }
    int excl = s[threadIdx.x] - v + bsum[blockIdx.x];
    if (i < N) { rowptr[i] = excl; cursor[i] = excl; }
}

__global__ void k_fill(const int* __restrict__ dstp, int* __restrict__ cursor,
                       int* __restrict__ eidx, int E) {
    int e = blockIdx.x * 256 + threadIdx.x;
    if (e < E) {
        int pos = atomicAdd(&cursor[dstp[e]], 1);
        eidx[pos] = e;
    }
}

// ---------------------------------------------------------------------------
// k_qkvr: batched GEMV with weights in LDS. Produces Q, K, V and the gate
// vector R = x@Ws + bs. 256 threads: quad = t&31 (channels quad*4..+3),
// sub = t>>5 (4 nodes each) -> 32 nodes per iteration, 4 nodes per thread.
// ---------------------------------------------------------------------------
__global__ __launch_bounds__(256) void k_qkvr(
        const float* __restrict__ xin, const float* __restrict__ nt,
        const float* __restrict__ rq, int din, int dshift, int N,
        const float* __restrict__ Wq, const float* __restrict__ bq,
        const float* __restrict__ Wk, const float* __restrict__ bk,
        const float* __restrict__ Wv, const float* __restrict__ bv,
        const float* __restrict__ Ws, const float* __restrict__ bs,
        float* __restrict__ Q, float* __restrict__ K,
        float* __restrict__ V, float* __restrict__ R) {
    __shared__ float w[4][32 * 128];
    __shared__ float bias[4][128];
    __shared__ float xs[32 * 33];
    int t = threadIdx.x;
    for (int i = t; i < din * 128; i += 256) {
        w[0][i] = Wq[i]; w[1][i] = Wk[i]; w[2][i] = Wv[i]; w[3][i] = Ws[i];
    }
    if (t < 128) {
        bias[0][t] = bq[t]; bias[1][t] = bk[t]; bias[2][t] = bv[t]; bias[3][t] = bs[t];
    }
    int quad = t & 31;
    int sub = t >> 5;
    int chunk = (N + (int)gridDim.x - 1) / (int)gridDim.x;
    chunk = (chunk + 31) & ~31;
    int nStart = blockIdx.x * chunk;
    int nEnd = min(nStart + chunk, N);
    for (int base = nStart; base < nEnd; base += 32) {
        __syncthreads();
        for (int i = t; i < 32 * din; i += 256) {
            int nl = i >> dshift, dd = i & (din - 1);
            int nn = base + nl;
            float xv = 0.f;
            if (nn < N) xv = (din == 2) ? (dd == 0 ? nt[nn] : rq[nn])
                                        : xin[(size_t)nn * din + dd];
            xs[nl * 33 + dd] = xv;
        }
        __syncthreads();
        float acc[4][4][4];  // [mat][node][comp]
#pragma unroll
        for (int m = 0; m < 4; ++m) {
#pragma unroll
            for (int k = 0; k < 4; ++k) {
#pragma unroll
                for (int c = 0; c < 4; ++c) acc[m][k][c] = bias[m][quad * 4 + c];
            }
        }
        for (int d = 0; d < din; ++d) {
            float4 wv[4];
#pragma unroll
            for (int m = 0; m < 4; ++m)
                wv[m] = *(const float4*)&w[m][d * 128 + quad * 4];
            float xv[4];
#pragma unroll
            for (int k = 0; k < 4; ++k) xv[k] = xs[(sub * 4 + k) * 33 + d];
#pragma unroll
            for (int m = 0; m < 4; ++m) {
#pragma unroll
                for (int k = 0; k < 4; ++k) {
                    acc[m][k][0] = fmaf(xv[k], wv[m].x, acc[m][k][0]);
                    acc[m][k][1] = fmaf(xv[k], wv[m].y, acc[m][k][1]);
                    acc[m][k][2] = fmaf(xv[k], wv[m].z, acc[m][k][2]);
                    acc[m][k][3] = fmaf(xv[k], wv[m].w, acc[m][k][3]);
                }
            }
        }
#pragma unroll
        for (int k = 0; k < 4; ++k) {
            int n = base + sub * 4 + k;
            if (n < N) {
                size_t o = (size_t)n * 128 + quad * 4;
                *(float4*)&Q[o] = *(float4*)acc[0][k];
                *(float4*)&K[o] = *(float4*)acc[1][k];
                *(float4*)&V[o] = *(float4*)acc[2][k];
                *(float4*)&R[o] = *(float4*)acc[3][k];
            }
        }
    }
}

// ---------------------------------------------------------------------------
// k_attn: one wave per dst node, 2 edge slots x 32 lanes, lane owns 4
// consecutive channels (head = lane>>3). Single-pass online softmax.
// No LDS, no __syncthreads.
// ---------------------------------------------------------------------------
__global__ __launch_bounds__(256) void k_attn(
        const int* __restrict__ srcp, const float* __restrict__ lat,
        const float* __restrict__ Q, const float* __restrict__ Kb,
        const float* __restrict__ Vb, const float* __restrict__ We,
        const float* __restrict__ R, const float* __restrict__ Wb,
        const int* __restrict__ rowptr, const int* __restrict__ deg,
        const int* __restrict__ eidx,
        float* __restrict__ A, int N) {
    int n = blockIdx.x * 4 + (threadIdx.x >> 6);
    if (n >= N) return;
    int l64 = threadIdx.x & 63;
    int slot = l64 >> 5;
    int lane = l64 & 31;

    const float4 q4 = *(const float4*)&Q[(size_t)n * 128 + lane * 4];
    const float4 we4 = *(const float4*)&We[lane * 4];
    int start = rowptr[n], d = deg[n];

    float m = -INFINITY, den = 0.f;
    float nx = 0.f, ny = 0.f, nz = 0.f, nw = 0.f;

    int idx = slot;
    bool have = idx < d;
    int e = 0, s = 0; float l = 0.f;
    if (have) { e = eidx[start + idx]; s = srcp[e]; l = lat[e]; }
    while (have) {
        int idx2 = idx + 2;
        bool have2 = idx2 < d;
        int e2 = 0, s2 = 0; float l2 = 0.f;
        if (have2) { e2 = eidx[start + idx2]; s2 = srcp[e2]; l2 = lat[e2]; }

        const float4 k4 = *(const float4*)&Kb[(size_t)s * 128 + lane * 4];
        const float4 v4 = *(const float4*)&Vb[(size_t)s * 128 + lane * 4];
        float t0 = q4.x * fmaf(l, we4.x, k4.x) + q4.y * fmaf(l, we4.y, k4.y)
                 + q4.z * fmaf(l, we4.z, k4.z) + q4.w * fmaf(l, we4.w, k4.w);
        t0 += __shfl_xor(t0, 1); t0 += __shfl_xor(t0, 2); t0 += __shfl_xor(t0, 4);
        float alpha = t0 * 0.17677669529663687f;  // 1/sqrt(32)

        float mn = fmaxf(m, alpha);
        float sc = expf(m - mn);       // m=-inf on first edge -> 0, no NaN
        float p = expf(alpha - mn);
        nx = nx * sc + p * fmaf(l, we4.x, v4.x);
        ny = ny * sc + p * fmaf(l, we4.y, v4.y);
        nz = nz * sc + p * fmaf(l, we4.z, v4.z);
        nw = nw * sc + p * fmaf(l, we4.w, v4.w);
        den = den * sc + p;
        m = mn;

        idx = idx2; e = e2; s = s2; l = l2; have = have2;
    }

    // merge the two slots (lane and lane+32 hold the same channels)
    float mo = __shfl_xor(m, 32);
    float mf = fmaxf(m, mo);
    float myscale = (m == -INFINITY) ? 0.f : expf(m - mf);
    nx *= myscale; ny *= myscale; nz *= myscale; nw *= myscale;
    den *= myscale;
    nx += __shfl_xor(nx, 32); ny += __shfl_xor(ny, 32);
    nz += __shfl_xor(nz, 32); nw += __shfl_xor(nw, 32);
    den += __shfl_xor(den, 32);
    float inv = 1.f / (den + 1e-16f);
    float ox = nx * inv, oy = ny * inv, oz = nz * inv, ow = nw * inv;

    // gate: beta = sigmoid([o, r, o-r] @ Wb); each slot covers all 128 ch
    const float4 r4 = *(const float4*)&R[(size_t)n * 128 + lane * 4];
    const float4 wb0 = *(const float4*)&Wb[lane * 4];
    const float4 wb1 = *(const float4*)&Wb[128 + lane * 4];
    const float4 wb2 = *(const float4*)&Wb[256 + lane * 4];
    float g = ox * wb0.x + r4.x * wb1.x + (ox - r4.x) * wb2.x
            + oy * wb0.y + r4.y * wb1.y + (oy - r4.y) * wb2.y
            + oz * wb0.z + r4.z * wb1.z + (oz - r4.z) * wb2.z
            + ow * wb0.w + r4.w * wb1.w + (ow - r4.w) * wb2.w;
    g += __shfl_xor(g, 1); g += __shfl_xor(g, 2); g += __shfl_xor(g, 4);
    g += __shfl_xor(g, 8); g += __shfl_xor(g, 16);
    float beta = 1.0f / (1.0f + expf(-g));

    if (slot == 0) {
        float4 outv;
        outv.x = beta * r4.x + (1.0f - beta) * ox;
        outv.y = beta * r4.y + (1.0f - beta) * oy;
        outv.z = beta * r4.z + (1.0f - beta) * oz;
        outv.w = beta * r4.w + (1.0f - beta) * ow;
        *(float4*)&A[(size_t)n * 128 + lane * 4] = outv;
    }
}

// ---------------------------------------------------------------------------
// K5: y = relu(x @ W + b) + per-column sum/sumsq (double atomics).
// ---------------------------------------------------------------------------
__global__ void k_linstats(const float* __restrict__ A, const float* __restrict__ W,
                           const float* __restrict__ b, float* __restrict__ Y,
                           double* __restrict__ SUM, double* __restrict__ SUMSQ, int N) {
    int t = blockIdx.x * 256 + threadIdx.x;
    int n = t >> 5, j = t & 31;
    float y = 0.f;
    if (n < N) {
        const float* xr = A + (size_t)n * 128;
        float acc = b[j];
        for (int d = 0; d < 128; d++) acc = fmaf(xr[d], W[d * 32 + j], acc);
        y = fmaxf(acc, 0.f);
        Y[(size_t)n * 32 + j] = y;
    }
    __shared__ float s1[256], s2[256];
    s1[threadIdx.x] = y; s2[threadIdx.x] = y * y;
    __syncthreads();
    for (int s = 128; s >= 32; s >>= 1) {
        if (threadIdx.x < s) { s1[threadIdx.x] += s1[threadIdx.x + s]; s2[threadIdx.x] += s2[threadIdx.x + s]; }
        __syncthreads();
    }
    if (threadIdx.x < 32) {
        atomicAdd(&SUM[threadIdx.x], (double)s1[threadIdx.x]);
        atomicAdd(&SUMSQ[threadIdx.x], (double)s2[threadIdx.x]);
    }
}

__global__ void k_bnapply(float* __restrict__ Y, const double* __restrict__ SUM,
                          const double* __restrict__ SUMSQ,
                          const float* __restrict__ g, const float* __restrict__ b, int N) {
    int t = blockIdx.x * 256 + threadIdx.x;
    if (t >= N * 32) return;
    int j = t & 31;
    double m = SUM[j] / N;
    double v = SUMSQ[j] / N - m * m;
    float mf = (float)m;
    float inv = rsqrtf((float)v + 1e-5f);
    Y[t] = (Y[t] - mf) * inv * g[j] + b[j];
}

__global__ void k_linear(const float* __restrict__ X, const float* __restrict__ W,
                         const float* __restrict__ b, float* __restrict__ Y,
                         int N, int Din, int Dout, int shift, int relu_flag) {
    int t = blockIdx.x * blockDim.x + threadIdx.x;
    if (t >= N * Dout) return;
    int n = t >> shift, j = t & (Dout - 1);
    const float* xr = X + (size_t)n * Din;
    float acc = b[j];
    for (int d = 0; d < Din; d++) acc = fmaf(xr[d], W[d * Dout + j], acc);
    if (relu_flag) acc = fmaxf(acc, 0.f);
    Y[t] = acc;
}

// ---------------------------------------------------------------------------
// Head kernels
// ---------------------------------------------------------------------------
__global__ void k_head1(const float* __restrict__ X3, const float* __restrict__ remW,
                        const float* __restrict__ remB, const int* __restrict__ active,
                        float* __restrict__ l1out, unsigned long long* __restrict__ slot1,
                        unsigned int* __restrict__ m1, int N) {
    int n = blockIdx.x * 256 + threadIdx.x;
    if (n >= N) return;
    const float* xr = X3 + (size_t)n * 64;
    float acc = remB[0];
    for (int d = 0; d < 64; d++) acc = fmaf(xr[d], remW[d], acc);
    float maskf = (active[n] == 1) ? 0.f : NEGF;
    float rm = (n < 15) ? ((maskf == 0.f) ? NEGF : 0.f) : maskf;
    float l1 = acc + rm;
    l1out[n] = l1;
    atomicMax(m1, fmono(l1));
    float z = l1 + gumbel_at(n, 0, N);
    unsigned long long p = ((unsigned long long)fmono(z) << 32) |
                           (unsigned long long)(0xFFFFFFFFu - (unsigned)n);
    atomicMax(slot1, p);
}

__global__ void k_head2(const float* __restrict__ X3, const float* __restrict__ addW,
                        const float* __restrict__ addB,
                        const unsigned long long* __restrict__ slot1,
                        float* __restrict__ tvec, int* __restrict__ a1buf) {
    int j = threadIdx.x;  // 64
    unsigned long long p = *slot1;
    int a1 = (int)(0xFFFFFFFFu - (unsigned)(p & 0xFFFFFFFFull));
    const float* xr = X3 + (size_t)a1 * 64;
    float acc = addB[j];
    for (int d = 0; d < 64; d++) acc = fmaf(xr[d], addW[d * 64 + j], acc);
    tvec[j] = tanhf(acc);
    if (j == 0) *a1buf = a1;
}

__global__ void k_head3(const float* __restrict__ X3, const float* __restrict__ tvec,
                        const int* __restrict__ active, const int* __restrict__ a1buf,
                        float* __restrict__ l2out, unsigned long long* __restrict__ slot2,
                        unsigned int* __restrict__ m2, int N) {
    int n = blockIdx.x * 256 + threadIdx.x;
    if (n >= N) return;
    const float* xr = X3 + (size_t)n * 64;
    float acc = 0.f;
    for (int d = 0; d < 64; d++) acc = fmaf(xr[d], tvec[d], acc);
    float maskf = (active[n] == 1) ? 0.f : NEGF;
    if (n == *a1buf) maskf = 0.f;
    float l2 = acc + maskf;
    l2out[n] = l2;
    atomicMax(m2, fmono(l2));
    float z = l2 + gumbel_at(n, 1, N);
    unsigned long long p = ((unsigned long long)fmono(z) << 32) |
                           (unsigned long long)(0xFFFFFFFFu - (unsigned)n);
    atomicMax(slot2, p);
}

__global__ void k_sumexp(const float* __restrict__ l1, const float* __restrict__ l2,
                         const unsigned int* __restrict__ m1, const unsigned int* __restrict__ m2,
                         float* __restrict__ se, int N) {
    int t = blockIdx.x * 256 + threadIdx.x;
    float M1 = funmono(*m1), M2 = funmono(*m2);
    float e1 = 0.f, e2 = 0.f;
    if (t < N) { e1 = expf(l1[t] - M1); e2 = expf(l2[t] - M2); }
    __shared__ float r1[256], r2[256];
    r1[threadIdx.x] = e1; r2[threadIdx.x] = e2;
    __syncthreads();
    for (int s = 128; s > 0; s >>= 1) {
        if (threadIdx.x < s) { r1[threadIdx.x] += r1[threadIdx.x + s]; r2[threadIdx.x] += r2[threadIdx.x + s]; }
        __syncthreads();
    }
    if (threadIdx.x == 0) { atomicAdd(&se[0], r1[0]); atomicAdd(&se[1], r2[0]); }
}

__global__ void k_final(const float* __restrict__ l1, const float* __restrict__ l2,
                        const unsigned long long* __restrict__ slot2,
                        const int* __restrict__ a1buf,
                        const unsigned int* __restrict__ m1, const unsigned int* __restrict__ m2,
                        const float* __restrict__ se, float* __restrict__ outTail, int N) {
    int a1 = *a1buf;
    int a2 = (int)(0xFFFFFFFFu - (unsigned)((*slot2) & 0xFFFFFFFFull));
    outTail[0] = (float)a1;
    outTail[1] = (float)a2;
    outTail[2] = l1[a1] - (funmono(*m1) + logf(se[0]));
    outTail[3] = l2[a2] - (funmono(*m2) + logf(se[1]));
}

// ---------------------------------------------------------------------------
// Host launcher
// ---------------------------------------------------------------------------
extern "C" void kernel_launch(void* const* d_in, const int* in_sizes, int n_in,
                              void* d_out, int out_size, void* d_ws, size_t ws_size,
                              hipStream_t stream) {
    const float* node_type = (const float*)d_in[0];
    const float* requests  = (const float*)d_in[1];
    const float* latency   = (const float*)d_in[2];
    const int* edge_index  = (const int*)d_in[3];
    const int* active      = (const int*)d_in[4];
    int N = in_sizes[0];
    int E = in_sizes[2];
    const int* src = edge_index;
    const int* dst = edge_index + E;
    float* out = (float*)d_out;

    char* base = (char*)d_ws;
    size_t off = 0;
    auto alloc = [&](size_t bytes) -> char* {
        char* p = base + off;
        off += (bytes + 255) & ~(size_t)255;
        return p;
    };
    float* A     = (float*)alloc((size_t)N * 128 * 4);
    float* Q     = (float*)alloc((size_t)N * 128 * 4);  // later emb y1
    float* Kb    = (float*)alloc((size_t)N * 128 * 4);  // later emb y2
    float* Vb    = (float*)alloc((size_t)N * 128 * 4);  // later emb y3 (x3)
    float* Rg    = (float*)alloc((size_t)N * 128 * 4);  // gate vector
    float* H32   = (float*)alloc((size_t)N * 32 * 4);
    int* deg     = (int*)alloc((size_t)N * 4);
    int* rowptr  = (int*)alloc((size_t)N * 4);
    int* cursor  = (int*)alloc((size_t)N * 4);
    int* eidx    = (int*)alloc((size_t)E * 4);
    int* bsum    = (int*)alloc(1024 * 4);
    double* SUM  = (double*)alloc(512);
    double* SUMSQ = SUM + 32;
    char* small  = alloc(1024);
    unsigned long long* slot1 = (unsigned long long*)small;
    unsigned long long* slot2 = slot1 + 1;
    unsigned int* m1 = (unsigned int*)(small + 16);
    unsigned int* m2 = m1 + 1;
    float* se = (float*)(small + 24);
    int* a1buf = (int*)(small + 32);
    float* tvec = (float*)(small + 64);

    int ng = (N + 255) / 256;
    int egE = (E + 255) / 256;
    int n32g = (N * 32 + 255) / 256;
    int nb = ng;

    // ---- CSR build ----
    (void)hipMemsetAsync(deg, 0, (size_t)N * 4, stream);
    k_hist<<<egE, 256, 0, stream>>>(dst, deg, E);
    k_scan1<<<nb, 256, 0, stream>>>(deg, bsum, N);
    k_scan2<<<1, 256, 0, stream>>>(bsum, nb);
    k_scan3<<<nb, 256, 0, stream>>>(deg, bsum, rowptr, cursor, N);
    k_fill<<<egE, 256, 0, stream>>>(dst, cursor, eidx, E);

    int attnBlocks = (N + 3) / 4;

    for (int L = 0; L < 5; ++L) {
        int din = L ? 32 : 2;
        int dshift = L ? 5 : 1;
        const float* xin = L ? H32 : nullptr;
        const float* Wq = L ? (const float*)d_in[19] + (size_t)(L - 1) * 4096 : (const float*)d_in[5];
        const float* bq = L ? (const float*)d_in[20] + (size_t)(L - 1) * 128  : (const float*)d_in[6];
        const float* Wk = L ? (const float*)d_in[21] + (size_t)(L - 1) * 4096 : (const float*)d_in[7];
        const float* bk = L ? (const float*)d_in[22] + (size_t)(L - 1) * 128  : (const float*)d_in[8];
        const float* Wv = L ? (const float*)d_in[23] + (size_t)(L - 1) * 4096 : (const float*)d_in[9];
        const float* bv = L ? (const float*)d_in[24] + (size_t)(L - 1) * 128  : (const float*)d_in[10];
        const float* We = L ? (const float*)d_in[25] + (size_t)(L - 1) * 128  : (const float*)d_in[11];
        const float* Ws = L ? (const float*)d_in[26] + (size_t)(L - 1) * 4096 : (const float*)d_in[12];
        const float* bs = L ? (const float*)d_in[27] + (size_t)(L - 1) * 128  : (const float*)d_in[13];
        const float* Wb = L ? (const float*)d_in[28] + (size_t)(L - 1) * 384  : (const float*)d_in[14];
        const float* tW = L ? (const float*)d_in[29] + (size_t)(L - 1) * 4096 : (const float*)d_in[15];
        const float* tb = L ? (const float*)d_in[30] + (size_t)(L - 1) * 32   : (const float*)d_in[16];
        const float* bg = L ? (const float*)d_in[31] + (size_t)(L - 1) * 32   : (const float*)d_in[17];
        const float* bb = L ? (const float*)d_in[32] + (size_t)(L - 1) * 32   : (const float*)d_in[18];

        k_qkvr<<<256, 256, 0, stream>>>(xin, node_type, requests, din, dshift, N,
                                        Wq, bq, Wk, bk, Wv, bv, Ws, bs,
                                        Q, Kb, Vb, Rg);
        k_attn<<<attnBlocks, 256, 0, stream>>>(src, latency, Q, Kb, Vb, We, Rg, Wb,
                                               rowptr, deg, eidx, A, N);
        (void)hipMemsetAsync(SUM, 0, 512, stream);
        k_linstats<<<n32g, 256, 0, stream>>>(A, tW, tb, H32, SUM, SUMSQ, N);
        k_bnapply<<<n32g, 256, 0, stream>>>(H32, SUM, SUMSQ, bg, bb, N);
    }

    // embedding MLP: 32 -> 128 -> 64 -> 64
    k_linear<<<(N * 128 + 255) / 256, 256, 0, stream>>>(
        H32, (const float*)d_in[33], (const float*)d_in[34], Q, N, 32, 128, 7, 1);
    k_linear<<<(N * 64 + 255) / 256, 256, 0, stream>>>(
        Q, (const float*)d_in[35], (const float*)d_in[36], Kb, N, 128, 64, 6, 1);
    k_linear<<<(N * 64 + 255) / 256, 256, 0, stream>>>(
        Kb, (const float*)d_in[37], (const float*)d_in[38], Vb, N, 64, 64, 6, 0);

    // head
    (void)hipMemsetAsync(small, 0, 64, stream);
    k_head1<<<ng, 256, 0, stream>>>(Vb, (const float*)d_in[39], (const float*)d_in[40],
                                    active, out, slot1, m1, N);
    k_head2<<<1, 64, 0, stream>>>(Vb, (const float*)d_in[41], (const float*)d_in[42],
                                  slot1, tvec, a1buf);
    k_head3<<<ng, 256, 0, stream>>>(Vb, tvec, active, a1buf, out + N, slot2, m2, N);
    k_sumexp<<<ng, 256, 0, stream>>>(out, out + N, m1, m2, se, N);
    k_final<<<1, 1, 0, stream>>>(out, out + N, slot2, a1buf, m1, m2, se, out + 2 * N, N);
}